// Round 7
// baseline (197.682 us; speedup 1.0000x reference)
//
#include <hip/hip_runtime.h>

#define N_CELL 100000
#define N_GENE 20000
#define DIM    128
#define N_EDGE 1000000

// --- sort geometry: 20 src-stripes x 2 dst-stripes = 40 tiles -------------
// cell stripe = 5000 rows (1.28 MB bf16), gene stripe = 10000 rows (2.56 MB)
#define NS_STRIPE 20
#define NTILE     40
#define NBLK_SORT 977            // x1024 edges = 1,000,448 >= N_EDGE

// work-queue chunk list (heavy/latency-long chunks first for mixing)
#define CH_PROJ 1250    // 16 gene rows each
#define CH_HIST 977     // 1024 edges each
#define CH_CAST 6250    // 512 float4 each
#define CH_CTAB 391
#define CH_GTAB 79
#define CH_TOTAL (CH_PROJ + CH_HIST + CH_CAST + CH_CTAB + CH_GTAB)
#define NB_WORK 2048    // 8 blocks/CU, all resident -> no ramp/tail

typedef float f32x4 __attribute__((ext_vector_type(4)));

// Round-to-nearest-even f32 -> bf16 (inputs finite; no NaN path needed).
__device__ inline unsigned short f2bf(float f) {
    unsigned u = __float_as_uint(f);
    u += 0x7fffu + ((u >> 16) & 1u);
    return (unsigned short)(u >> 16);
}

// HW bf16 pair-dot: acc += a.lo*b.lo + a.hi*b.hi (f32 accumulate).
__device__ inline void dot2(float& acc, unsigned a, unsigned b) {
    asm("v_dot2_f32_bf16 %0, %1, %2, %0" : "+v"(acc) : "v"(a), "v"(b));
}

// ss = s/5000 via magic mul (exact for s < 1.5M); ds = d/10000.
__device__ inline int tile_of(int s, int d) {
    const int ss = (int)(((unsigned long long)s * 429497ULL) >> 31);  // 0..19
    const int ds = (d >= 10000) ? 1 : 0;                              // 0..1
    return ds * NS_STRIPE + ss;
}

// pack (src:17b, dst:15b) into one u32. s<131072, d<32768.
__device__ inline unsigned pack_sd(int s, int d) {
    return ((unsigned)s << 15) | (unsigned)d;
}

// ---------------------------------------------------------------------------
// Persistent work-queue prep kernel. 2048 resident blocks pull chunks from a
// global cursor: [proj | hist | cast | ctab | gtab]. Proj first (longest per
// chunk); BW-bound cast chunks fill in around it -> phases overlap instead of
// serializing (R6: 31% occupancy from ramp/tail).
// Work assignment varies per run; outputs are per-chunk-owned -> deterministic.
// ---------------------------------------------------------------------------
__global__ __launch_bounds__(256) void work_kernel(
    const float* __restrict__ gene_z,
    const float* __restrict__ W,
    const float* __restrict__ b,
    ushort* __restrict__ gene_projb,
    const float* __restrict__ cell_z,
    ushort4* __restrict__ cell_zb4,
    const int*   __restrict__ src_idx,
    const int*   __restrict__ dst_idx,
    const int*   __restrict__ cell_n_id,
    const int*   __restrict__ gene_n_id,
    const float* __restrict__ cell_scale,
    const float* __restrict__ cell_bias,
    const float* __restrict__ cell_std,
    const float* __restrict__ gene_scale,
    const float* __restrict__ gene_bias,
    const float* __restrict__ gene_std,
    float4* __restrict__ cell_p4,
    float4* __restrict__ gene_p4,
    int* __restrict__ counts,       // [NTILE][NBLK_SORT], null -> skip hist
    int* __restrict__ cursor)
{
    __shared__ float zlds[16][DIM];     // 8 KB (proj chunks)
    __shared__ int   lcnt[NTILE];       // hist chunks
    __shared__ int   chunk_s;

    const int tid = threadIdx.x;

    for (;;) {
        if (tid == 0) chunk_s = atomicAdd(cursor, 1);
        __syncthreads();                 // also fences LDS reuse across chunks
        int c = chunk_s;
        if (c >= CH_TOTAL) return;

        if (c < CH_PROJ) {
            // ---- gene projection: 16 rows, 8 rows per thread ----
            const int row0 = c * 16;
            const f32x4* Z4  = (const f32x4*)(gene_z + (long)row0 * DIM);
            f32x4*       zl4 = (f32x4*)&zlds[0][0];
            zl4[tid]       = Z4[tid];
            zl4[tid + 256] = Z4[tid + 256];
            __syncthreads();

            const int col   = tid & 127;
            const int rbase = (tid >> 7) * 8;   // 0 or 8

            const float bias = b[col];
            float acc[8];
            #pragma unroll
            for (int r = 0; r < 8; ++r) acc[r] = bias;

            for (int k4 = 0; k4 < DIM / 4; ++k4) {
                const float w0 = W[(k4 * 4 + 0) * DIM + col];
                const float w1 = W[(k4 * 4 + 1) * DIM + col];
                const float w2 = W[(k4 * 4 + 2) * DIM + col];
                const float w3 = W[(k4 * 4 + 3) * DIM + col];
                #pragma unroll
                for (int rp = 0; rp < 4; ++rp) {
                    const float4 za = ((const float4*)&zlds[rbase + 2*rp][0])[k4];
                    const float4 zb = ((const float4*)&zlds[rbase + 2*rp + 1][0])[k4];
                    acc[2*rp]     = fmaf(za.x, w0, fmaf(za.y, w1,
                                    fmaf(za.z, w2, fmaf(za.w, w3, acc[2*rp]))));
                    acc[2*rp + 1] = fmaf(zb.x, w0, fmaf(zb.y, w1,
                                    fmaf(zb.z, w2, fmaf(zb.w, w3, acc[2*rp + 1]))));
                }
            }
            #pragma unroll
            for (int r = 0; r < 8; ++r) {
                const float v = acc[r];
                gene_projb[(long)(row0 + rbase + r) * DIM + col] =
                    f2bf(v > 0.f ? v : 0.01f * v);
            }
            continue;
        }
        c -= CH_PROJ;

        if (c < CH_HIST) {
            if (!counts) continue;
            if (tid < NTILE) lcnt[tid] = 0;
            __syncthreads();
            #pragma unroll
            for (int q = 0; q < 4; ++q) {
                const int e = c * 1024 + q * 256 + tid;
                if (e < N_EDGE) {
                    const int t = tile_of(src_idx[e], dst_idx[e]);
                    atomicAdd(&lcnt[t], 1);
                }
            }
            __syncthreads();
            if (tid < NTILE) counts[tid * NBLK_SORT + c] = lcnt[tid];
            continue;
        }
        c -= CH_HIST;

        if (c < CH_CAST) {
            // ---- cell_z cast f32 -> bf16, 2 float4 per thread ----
            const f32x4* in4 = (const f32x4*)cell_z;
            const int base = c * 512 + tid;
            const f32x4 v0 = in4[base];
            const f32x4 v1 = in4[base + 256];
            ushort4 o0, o1;
            o0.x = f2bf(v0.x); o0.y = f2bf(v0.y); o0.z = f2bf(v0.z); o0.w = f2bf(v0.w);
            o1.x = f2bf(v1.x); o1.y = f2bf(v1.y); o1.z = f2bf(v1.z); o1.w = f2bf(v1.w);
            cell_zb4[base]       = o0;
            cell_zb4[base + 256] = o1;
            continue;
        }
        c -= CH_CAST;

        if (c < CH_CTAB) {
            if (!cell_p4) continue;
            const int cc = c * 256 + tid;
            if (cc < N_CELL) {
                const int id = cell_n_id[cc];
                cell_p4[cc] = make_float4(cell_scale[id], cell_bias[id],
                                          cell_std[id], 0.f);
            }
            continue;
        }
        c -= CH_CTAB;

        if (!gene_p4) continue;
        const int g = c * 256 + tid;
        if (g < N_GENE) {
            const int id = gene_n_id[g];
            gene_p4[g] = make_float4(gene_scale[id], gene_bias[id],
                                     gene_std[id], 0.f);
        }
    }
}

// ---------------------------------------------------------------------------
// scanA: per tile (blockIdx = tile), exclusive-scan its 977 per-block counts
// in place (-> per-(tile,block) offsets) and emit the tile total.
// ---------------------------------------------------------------------------
__global__ __launch_bounds__(256) void scanA_kernel(
    int* __restrict__ counts, int* __restrict__ totals)
{
    __shared__ int sd[256];
    const int t   = blockIdx.x;
    const int tid = threadIdx.x;
    int carry = 0;
    for (int c = 0; c < 4; ++c) {
        const int idx = c * 256 + tid;
        const int val = (idx < NBLK_SORT) ? counts[t * NBLK_SORT + idx] : 0;
        sd[tid] = val;
        __syncthreads();
        #pragma unroll
        for (int off = 1; off < 256; off <<= 1) {
            const int tmp = (tid >= off) ? sd[tid - off] : 0;
            __syncthreads();
            sd[tid] += tmp;
            __syncthreads();
        }
        const int incl = sd[tid];
        const int ctot = sd[255];
        if (idx < NBLK_SORT) counts[t * NBLK_SORT + idx] = carry + incl - val;
        carry += ctot;
        __syncthreads();
    }
    if (tid == 0) totals[t] = carry;
}

// ---------------------------------------------------------------------------
// scatter: write packed (src,dst) to sorted position; write rank[e]
// (= sorted position) COALESCED in e-order. bases scanned in-block (40 elems).
// ---------------------------------------------------------------------------
__global__ __launch_bounds__(256) void scatter_kernel(
    const int* __restrict__ src_idx,
    const int* __restrict__ dst_idx,
    const int* __restrict__ counts,   // per-(tile,block) offsets
    const int* __restrict__ totals,
    unsigned* __restrict__ sorted_p,
    int*      __restrict__ rank)
{
    __shared__ int lcnt[NTILE];
    __shared__ int sbase[NTILE];
    __shared__ int lbase[NTILE];
    const int tid = threadIdx.x;
    const int blk = blockIdx.x;
    if (tid < NTILE) lcnt[tid] = 0;
    __syncthreads();

    int ts[4], rs[4], ss[4], ds[4];
    #pragma unroll
    for (int c = 0; c < 4; ++c) {
        const int e = blk * 1024 + c * 256 + tid;
        if (e < N_EDGE) {
            ss[c] = src_idx[e];
            ds[c] = dst_idx[e];
            ts[c] = tile_of(ss[c], ds[c]);
            rs[c] = atomicAdd(&lcnt[ts[c]], 1);
        } else { ts[c] = -1; rs[c] = 0; ss[c] = 0; ds[c] = 0; }
    }
    __syncthreads();
    if (tid == 0) {
        int s = 0;
        for (int i = 0; i < NTILE; ++i) { sbase[i] = s; s += totals[i]; }
    }
    __syncthreads();
    if (tid < NTILE) lbase[tid] = sbase[tid] + counts[tid * NBLK_SORT + blk];
    __syncthreads();

    #pragma unroll
    for (int c = 0; c < 4; ++c) {
        const int e = blk * 1024 + c * 256 + tid;
        if (ts[c] >= 0) {
            const int pos = lbase[ts[c]] + rs[c];
            sorted_p[pos] = pack_sd(ss[c], ds[c]);
            rank[e] = pos;                       // coalesced in e
        }
    }
}

// ---------------------------------------------------------------------------
// Sorted edge kernel: 16 lanes/edge, 4 edges/group, 64 edges/block.
// Reads packed u32 stream; writes res[pos]={loc,std} COALESCED (sorted order).
// XCD-chunk swizzle: each XCD walks a contiguous sorted range
// (tile working set 1.28+2.56=3.84MB fits the 4MB per-XCD L2).
// ---------------------------------------------------------------------------
__global__ __launch_bounds__(256) void edge_sorted_kernel(
    const ushort* __restrict__ cell_zb,
    const ushort* __restrict__ gene_projb,
    const unsigned* __restrict__ sorted_p,
    const float4* __restrict__ cell_p4,
    const float4* __restrict__ gene_p4,
    float2* __restrict__ res)
{
    // bijective XCD chunk swizzle (m204): nwg=15625, q=1953, r=1
    const int wg  = blockIdx.x;
    const int xcd = wg & 7;
    const int sub = wg >> 3;
    const int q = 15625 / 8, r = 15625 % 8;
    const int swz = ((xcd < r) ? xcd * (q + 1) : r * (q + 1) + (xcd - r) * q) + sub;

    const int tid  = threadIdx.x;
    const int lane = tid & 15;
    const int grp  = swz * 16 + (tid >> 4);

    const uint4 p = ((const uint4*)sorted_p)[grp];
    const int s0 = (int)(p.x >> 15), d0 = (int)(p.x & 0x7fffu);
    const int s1 = (int)(p.y >> 15), d1 = (int)(p.y & 0x7fffu);
    const int s2 = (int)(p.z >> 15), d2 = (int)(p.z & 0x7fffu);
    const int s3 = (int)(p.w >> 15), d3 = (int)(p.w & 0x7fffu);

    uint4 a0 = ((const uint4*)(cell_zb    + (long)s0 * DIM))[lane];
    uint4 a1 = ((const uint4*)(cell_zb    + (long)s1 * DIM))[lane];
    uint4 a2 = ((const uint4*)(cell_zb    + (long)s2 * DIM))[lane];
    uint4 a3 = ((const uint4*)(cell_zb    + (long)s3 * DIM))[lane];
    uint4 v0 = ((const uint4*)(gene_projb + (long)d0 * DIM))[lane];
    uint4 v1 = ((const uint4*)(gene_projb + (long)d1 * DIM))[lane];
    uint4 v2 = ((const uint4*)(gene_projb + (long)d2 * DIM))[lane];
    uint4 v3 = ((const uint4*)(gene_projb + (long)d3 * DIM))[lane];

    float dot0 = 0.f, dot1 = 0.f, dot2v = 0.f, dot3 = 0.f;
    dot2(dot0, a0.x, v0.x); dot2(dot0, a0.y, v0.y);
    dot2(dot0, a0.z, v0.z); dot2(dot0, a0.w, v0.w);
    dot2(dot1, a1.x, v1.x); dot2(dot1, a1.y, v1.y);
    dot2(dot1, a1.z, v1.z); dot2(dot1, a1.w, v1.w);
    dot2(dot2v, a2.x, v2.x); dot2(dot2v, a2.y, v2.y);
    dot2(dot2v, a2.z, v2.z); dot2(dot2v, a2.w, v2.w);
    dot2(dot3, a3.x, v3.x); dot2(dot3, a3.y, v3.y);
    dot2(dot3, a3.z, v3.z); dot2(dot3, a3.w, v3.w);

    #define RED(d)                 \
        d += __shfl_xor(d, 1);     \
        d += __shfl_xor(d, 2);     \
        d += __shfl_xor(d, 4);     \
        d += __shfl_xor(d, 8);
    RED(dot0) RED(dot1) RED(dot2v) RED(dot3)
    #undef RED

    if (lane < 4) {
        const float dj = (lane & 2) ? ((lane & 1) ? dot3 : dot2v)
                                    : ((lane & 1) ? dot1 : dot0);
        const int sj   = (lane & 2) ? ((lane & 1) ? s3 : s2)
                                    : ((lane & 1) ? s1 : s0);
        const int djx  = (lane & 2) ? ((lane & 1) ? d3 : d2)
                                    : ((lane & 1) ? d1 : d0);
        const float4 cs = cell_p4[sj];
        const float4 gs = gene_p4[djx];
        res[grp * 4 + lane] =
            make_float2(dj * cs.x * gs.x + cs.y + gs.y, cs.z * gs.z);
    }
}

// ---------------------------------------------------------------------------
// fixup: out[e] = res[rank[e]].  Coalesced rank read + out writes; res reads
// cluster into ~40 short runs per 1024-edge window (scatter block structure)
// -> near-line-efficient. 4 edges per thread.
// ---------------------------------------------------------------------------
__global__ __launch_bounds__(256) void fixup_kernel(
    const int*    __restrict__ rank,
    const float2* __restrict__ res,
    float* __restrict__ out)
{
    const int e0 = (blockIdx.x * 256 + threadIdx.x) * 4;
    if (e0 >= N_EDGE) return;
    const int4 r4 = *(const int4*)(rank + e0);
    const float2 r0 = res[r4.x];
    const float2 r1 = res[r4.y];
    const float2 r2 = res[r4.z];
    const float2 r3 = res[r4.w];
    *(float4*)(out + e0)          = make_float4(r0.x, r1.x, r2.x, r3.x);
    *(float4*)(out + N_EDGE + e0) = make_float4(r0.y, r1.y, r2.y, r3.y);
}

// ---------------------------------------------------------------------------
// Fallback unsorted edge kernel if workspace too small for sort.
// ---------------------------------------------------------------------------
template<bool TAB>
__global__ __launch_bounds__(256) void edge_kernel(
    const ushort* __restrict__ cell_zb,
    const ushort* __restrict__ gene_projb,
    const int*   __restrict__ src_idx,
    const int*   __restrict__ dst_idx,
    const int*   __restrict__ cell_n_id,
    const int*   __restrict__ gene_n_id,
    const float* __restrict__ cell_scale,
    const float* __restrict__ cell_bias,
    const float* __restrict__ cell_std,
    const float* __restrict__ gene_scale,
    const float* __restrict__ gene_bias,
    const float* __restrict__ gene_std,
    const float4* __restrict__ cell_p4,
    const float4* __restrict__ gene_p4,
    float* __restrict__ out)
{
    const int tid  = threadIdx.x;
    const int lane = tid & 15;
    const int grp  = blockIdx.x * 16 + (tid >> 4);
    const int e0   = grp * 4;

    const int4 s4 = ((const int4*)src_idx)[grp];
    const int4 d4 = ((const int4*)dst_idx)[grp];

    uint4 a0 = ((const uint4*)(cell_zb    + (long)s4.x * DIM))[lane];
    uint4 a1 = ((const uint4*)(cell_zb    + (long)s4.y * DIM))[lane];
    uint4 a2 = ((const uint4*)(cell_zb    + (long)s4.z * DIM))[lane];
    uint4 a3 = ((const uint4*)(cell_zb    + (long)s4.w * DIM))[lane];
    uint4 v0 = ((const uint4*)(gene_projb + (long)d4.x * DIM))[lane];
    uint4 v1 = ((const uint4*)(gene_projb + (long)d4.y * DIM))[lane];
    uint4 v2 = ((const uint4*)(gene_projb + (long)d4.z * DIM))[lane];
    uint4 v3 = ((const uint4*)(gene_projb + (long)d4.w * DIM))[lane];

    float dot0 = 0.f, dot1 = 0.f, dot2v = 0.f, dot3 = 0.f;
    dot2(dot0, a0.x, v0.x); dot2(dot0, a0.y, v0.y);
    dot2(dot0, a0.z, v0.z); dot2(dot0, a0.w, v0.w);
    dot2(dot1, a1.x, v1.x); dot2(dot1, a1.y, v1.y);
    dot2(dot1, a1.z, v1.z); dot2(dot1, a1.w, v1.w);
    dot2(dot2v, a2.x, v2.x); dot2(dot2v, a2.y, v2.y);
    dot2(dot2v, a2.z, v2.z); dot2(dot2v, a2.w, v2.w);
    dot2(dot3, a3.x, v3.x); dot2(dot3, a3.y, v3.y);
    dot2(dot3, a3.z, v3.z); dot2(dot3, a3.w, v3.w);

    #define RED(d)                 \
        d += __shfl_xor(d, 1);     \
        d += __shfl_xor(d, 2);     \
        d += __shfl_xor(d, 4);     \
        d += __shfl_xor(d, 8);
    RED(dot0) RED(dot1) RED(dot2v) RED(dot3)
    #undef RED

    if (lane < 4) {
        const float dj = (lane & 2) ? ((lane & 1) ? dot3 : dot2v)
                                    : ((lane & 1) ? dot1 : dot0);
        const int sj   = (lane & 2) ? ((lane & 1) ? s4.w : s4.z)
                                    : ((lane & 1) ? s4.y : s4.x);
        const int djx  = (lane & 2) ? ((lane & 1) ? d4.w : d4.z)
                                    : ((lane & 1) ? d4.y : d4.x);
        float sc_s, b_s, sd_s, sc_d, b_d, sd_d;
        if (TAB) {
            const float4 cs = cell_p4[sj];
            const float4 gs = gene_p4[djx];
            sc_s = cs.x; b_s = cs.y; sd_s = cs.z;
            sc_d = gs.x; b_d = gs.y; sd_d = gs.z;
        } else {
            const int sid = cell_n_id[sj];
            const int did = gene_n_id[djx];
            sc_s = cell_scale[sid]; b_s = cell_bias[sid]; sd_s = cell_std[sid];
            sc_d = gene_scale[did]; b_d = gene_bias[did]; sd_d = gene_std[did];
        }
        const int e = e0 + lane;
        out[e]          = dj * sc_s * sc_d + b_s + b_d;
        out[N_EDGE + e] = sd_s * sd_d;
    }
}

extern "C" void kernel_launch(void* const* d_in, const int* in_sizes, int n_in,
                              void* d_out, int out_size, void* d_ws, size_t ws_size,
                              hipStream_t stream) {
    const float* cell_z     = (const float*)d_in[0];
    const float* gene_z     = (const float*)d_in[1];
    const float* W_gene     = (const float*)d_in[2];
    const float* b_gene     = (const float*)d_in[3];
    const float* cell_scale = (const float*)d_in[4];
    const float* cell_bias  = (const float*)d_in[5];
    const float* cell_std   = (const float*)d_in[6];
    const float* gene_scale = (const float*)d_in[7];
    const float* gene_bias  = (const float*)d_in[8];
    const float* gene_std   = (const float*)d_in[9];
    const int*   src_idx    = (const int*)d_in[10];
    const int*   dst_idx    = (const int*)d_in[11];
    const int*   cell_n_id  = (const int*)d_in[12];
    const int*   gene_n_id  = (const int*)d_in[13];

    // Workspace layout:
    char* ws = (char*)d_ws;
    size_t off = 0;
    ushort* gene_projb = (ushort*)(ws + off); off += (size_t)N_GENE * DIM * 2;  // 5.12 MB
    ushort* cell_zb    = (ushort*)(ws + off); off += (size_t)N_CELL * DIM * 2;  // 25.6 MB
    int*    cursor     = (int*)(ws + off);    off += 256;
    const size_t base_need = off;

    // tables (1.92 MB)
    float4* cell_p4 = nullptr; float4* gene_p4 = nullptr;
    size_t off_tab = off;
    const size_t tab_need = (size_t)N_CELL * 16 + (size_t)N_GENE * 16;

    // sort structures (~16.2 MB)
    unsigned* sorted_p = nullptr; int* rank = nullptr; float2* res = nullptr;
    int* counts = nullptr; int* totals = nullptr;
    const size_t sort_need = (size_t)N_EDGE * 4      // sorted_p
                           + (size_t)N_EDGE * 4      // rank
                           + (size_t)N_EDGE * 8      // res
                           + (size_t)NTILE * NBLK_SORT * 4 + 256;

    const bool tab = (ws_size >= base_need + tab_need);
    const bool srt = tab && (ws_size >= base_need + tab_need + sort_need);

    if (tab) {
        cell_p4 = (float4*)(ws + off_tab);
        gene_p4 = (float4*)(ws + off_tab + (size_t)N_CELL * 16);
        off = off_tab + tab_need;
    }
    if (srt) {
        sorted_p = (unsigned*)(ws + off); off += (size_t)N_EDGE * 4;
        rank     = (int*)(ws + off);      off += (size_t)N_EDGE * 4;
        res      = (float2*)(ws + off);   off += (size_t)N_EDGE * 8;
        counts   = (int*)(ws + off);      off += (size_t)NTILE * NBLK_SORT * 4;
        totals   = (int*)(ws + off);      off += 256;
    }

    float* out = (float*)d_out;

    hipMemsetAsync(cursor, 0, sizeof(int), stream);
    work_kernel<<<NB_WORK, 256, 0, stream>>>(
        gene_z, W_gene, b_gene, gene_projb,
        cell_z, (ushort4*)cell_zb,
        src_idx, dst_idx, cell_n_id, gene_n_id,
        cell_scale, cell_bias, cell_std,
        gene_scale, gene_bias, gene_std,
        cell_p4, gene_p4, counts, cursor);

    if (srt) {
        scanA_kernel<<<NTILE, 256, 0, stream>>>(counts, totals);
        scatter_kernel<<<NBLK_SORT, 256, 0, stream>>>(
            src_idx, dst_idx, counts, totals, sorted_p, rank);
        edge_sorted_kernel<<<N_EDGE / 64, 256, 0, stream>>>(
            cell_zb, gene_projb, sorted_p, cell_p4, gene_p4, res);
        fixup_kernel<<<(N_EDGE / 4 + 255) / 256, 256, 0, stream>>>(rank, res, out);
    } else if (tab) {
        edge_kernel<true><<<N_EDGE / 64, 256, 0, stream>>>(
            cell_zb, gene_projb, src_idx, dst_idx, cell_n_id, gene_n_id,
            cell_scale, cell_bias, cell_std, gene_scale, gene_bias, gene_std,
            cell_p4, gene_p4, out);
    } else {
        edge_kernel<false><<<N_EDGE / 64, 256, 0, stream>>>(
            cell_zb, gene_projb, src_idx, dst_idx, cell_n_id, gene_n_id,
            cell_scale, cell_bias, cell_std, gene_scale, gene_bias, gene_std,
            nullptr, nullptr, out);
    }
}

// Round 8
// 85.928 us; speedup vs baseline: 2.3006x; 2.3006x over previous
//
#include <hip/hip_runtime.h>

#define N_CELL 100000
#define N_GENE 20000
#define DIM    128
#define N_EDGE 1000000

// --- sort geometry: 20 src-stripes x 2 dst-stripes = 40 tiles -------------
// cell stripe = 5000 rows (1.28 MB bf16), gene stripe = 10000 rows (2.56 MB)
#define NS_STRIPE 20
#define NTILE     40
#define NBLK_SORT 977            // x1024 edges = 1,000,448 >= N_EDGE

// prep_kernel block-range partition. ORDER MATTERS (in-order dispatch):
// long VALU/LDS-bound proj blocks FIRST so they overlap the HBM-bound cast
// stream; short cast blocks LAST so the drain tail is short blocks at full
// occupancy. (R6 had cast first -> proj ran on a draining machine, 31% occ.
// R7's atomic work-queue serialized on one cacheline -> 3.4x worse.)
#define NB_PROJ 1250    // 16 gene rows each
#define NB_HIST 977     // 1024 edges each
#define NB_CTAB 391
#define NB_GTAB 79
#define NB_CAST 6250    // 512 float4 each
#define NB_PREP (NB_PROJ + NB_HIST + NB_CTAB + NB_GTAB + NB_CAST)

typedef float f32x4 __attribute__((ext_vector_type(4)));

// Round-to-nearest-even f32 -> bf16 (inputs finite; no NaN path needed).
__device__ inline unsigned short f2bf(float f) {
    unsigned u = __float_as_uint(f);
    u += 0x7fffu + ((u >> 16) & 1u);
    return (unsigned short)(u >> 16);
}

// HW bf16 pair-dot: acc += a.lo*b.lo + a.hi*b.hi (f32 accumulate).
__device__ inline void dot2(float& acc, unsigned a, unsigned b) {
    asm("v_dot2_f32_bf16 %0, %1, %2, %0" : "+v"(acc) : "v"(a), "v"(b));
}

// ss = s/5000 via magic mul (exact for s < 1.5M); ds = d/10000.
__device__ inline int tile_of(int s, int d) {
    const int ss = (int)(((unsigned long long)s * 429497ULL) >> 31);  // 0..19
    const int ds = (d >= 10000) ? 1 : 0;                              // 0..1
    return ds * NS_STRIPE + ss;
}

// pack (src:17b, dst:15b) into one u32. s<131072, d<32768.
__device__ inline unsigned pack_sd(int s, int d) {
    return ((unsigned)s << 15) | (unsigned)d;
}

// ---------------------------------------------------------------------------
// Fused prep kernel, static block ranges (see ordering note above):
//   [0, NB_PROJ)   : gene_proj = leaky_relu(gene_z @ W + b) -> bf16
//   [+NB_HIST)     : per-block tile histogram of edges (skipped if !counts)
//   [+NB_CTAB)     : cell_p4[c] = {scale,bias,std,0}[cell_n_id[c]]
//   [+NB_GTAB)     : gene_p4[g] = {scale,bias,std,0}[gene_n_id[g]]
//   [+NB_CAST)     : cast cell_z f32 -> bf16 (2 float4/thread)
// ---------------------------------------------------------------------------
__global__ __launch_bounds__(256) void prep_kernel(
    const float* __restrict__ gene_z,
    const float* __restrict__ W,
    const float* __restrict__ b,
    ushort* __restrict__ gene_projb,
    const float* __restrict__ cell_z,
    ushort4* __restrict__ cell_zb4,
    const int*   __restrict__ src_idx,
    const int*   __restrict__ dst_idx,
    const int*   __restrict__ cell_n_id,
    const int*   __restrict__ gene_n_id,
    const float* __restrict__ cell_scale,
    const float* __restrict__ cell_bias,
    const float* __restrict__ cell_std,
    const float* __restrict__ gene_scale,
    const float* __restrict__ gene_bias,
    const float* __restrict__ gene_std,
    float4* __restrict__ cell_p4,
    float4* __restrict__ gene_p4,
    int* __restrict__ counts)       // [NTILE][NBLK_SORT], null -> skip hist
{
    __shared__ float zlds[16][DIM];     // 8 KB; hist aliases it as int*

    const int tid = threadIdx.x;
    int blk = blockIdx.x;

    if (blk < NB_PROJ) {
        // ---- gene projection: 16 rows per block, 8 rows per thread ----
        const int row0 = blk * 16;
        const f32x4* Z4  = (const f32x4*)(gene_z + (long)row0 * DIM);
        f32x4*       zl4 = (f32x4*)&zlds[0][0];
        zl4[tid]       = Z4[tid];
        zl4[tid + 256] = Z4[tid + 256];
        __syncthreads();

        const int col   = tid & 127;
        const int rbase = (tid >> 7) * 8;   // 0 or 8

        const float bias = b[col];
        float acc[8];
        #pragma unroll
        for (int r = 0; r < 8; ++r) acc[r] = bias;

        for (int k4 = 0; k4 < DIM / 4; ++k4) {
            const float w0 = W[(k4 * 4 + 0) * DIM + col];
            const float w1 = W[(k4 * 4 + 1) * DIM + col];
            const float w2 = W[(k4 * 4 + 2) * DIM + col];
            const float w3 = W[(k4 * 4 + 3) * DIM + col];
            #pragma unroll
            for (int rp = 0; rp < 4; ++rp) {
                const float4 za = ((const float4*)&zlds[rbase + 2*rp][0])[k4];
                const float4 zb = ((const float4*)&zlds[rbase + 2*rp + 1][0])[k4];
                acc[2*rp]     = fmaf(za.x, w0, fmaf(za.y, w1,
                                fmaf(za.z, w2, fmaf(za.w, w3, acc[2*rp]))));
                acc[2*rp + 1] = fmaf(zb.x, w0, fmaf(zb.y, w1,
                                fmaf(zb.z, w2, fmaf(zb.w, w3, acc[2*rp + 1]))));
            }
        }
        #pragma unroll
        for (int r = 0; r < 8; ++r) {
            const float v = acc[r];
            gene_projb[(long)(row0 + rbase + r) * DIM + col] =
                f2bf(v > 0.f ? v : 0.01f * v);
        }
        return;
    }
    blk -= NB_PROJ;

    if (blk < NB_HIST) {
        if (!counts) return;
        int* lcnt = (int*)&zlds[0][0];
        if (tid < NTILE) lcnt[tid] = 0;
        __syncthreads();
        #pragma unroll
        for (int q = 0; q < 4; ++q) {
            const int e = blk * 1024 + q * 256 + tid;
            if (e < N_EDGE) {
                const int t = tile_of(src_idx[e], dst_idx[e]);
                atomicAdd(&lcnt[t], 1);
            }
        }
        __syncthreads();
        if (tid < NTILE) counts[tid * NBLK_SORT + blk] = lcnt[tid];
        return;
    }
    blk -= NB_HIST;

    if (blk < NB_CTAB) {
        if (!cell_p4) return;
        const int c = blk * 256 + tid;
        if (c < N_CELL) {
            const int id = cell_n_id[c];
            cell_p4[c] = make_float4(cell_scale[id], cell_bias[id],
                                     cell_std[id], 0.f);
        }
        return;
    }
    blk -= NB_CTAB;

    if (blk < NB_GTAB) {
        if (!gene_p4) return;
        const int g = blk * 256 + tid;
        if (g < N_GENE) {
            const int id = gene_n_id[g];
            gene_p4[g] = make_float4(gene_scale[id], gene_bias[id],
                                     gene_std[id], 0.f);
        }
        return;
    }
    blk -= NB_GTAB;

    // ---- cell_z cast f32 -> bf16, 2 float4 per thread ----
    const f32x4* in4 = (const f32x4*)cell_z;
    const int base = blk * 512 + tid;
    const f32x4 v0 = in4[base];
    const f32x4 v1 = in4[base + 256];
    ushort4 o0, o1;
    o0.x = f2bf(v0.x); o0.y = f2bf(v0.y); o0.z = f2bf(v0.z); o0.w = f2bf(v0.w);
    o1.x = f2bf(v1.x); o1.y = f2bf(v1.y); o1.z = f2bf(v1.z); o1.w = f2bf(v1.w);
    cell_zb4[base]       = o0;
    cell_zb4[base + 256] = o1;
}

// ---------------------------------------------------------------------------
// scanA: per tile (blockIdx = tile), exclusive-scan its 977 per-block counts
// in place (-> per-(tile,block) offsets) and emit the tile total.
// ---------------------------------------------------------------------------
__global__ __launch_bounds__(256) void scanA_kernel(
    int* __restrict__ counts, int* __restrict__ totals)
{
    __shared__ int sd[256];
    const int t   = blockIdx.x;
    const int tid = threadIdx.x;
    int carry = 0;
    for (int c = 0; c < 4; ++c) {
        const int idx = c * 256 + tid;
        const int val = (idx < NBLK_SORT) ? counts[t * NBLK_SORT + idx] : 0;
        sd[tid] = val;
        __syncthreads();
        #pragma unroll
        for (int off = 1; off < 256; off <<= 1) {
            const int tmp = (tid >= off) ? sd[tid - off] : 0;
            __syncthreads();
            sd[tid] += tmp;
            __syncthreads();
        }
        const int incl = sd[tid];
        const int ctot = sd[255];
        if (idx < NBLK_SORT) counts[t * NBLK_SORT + idx] = carry + incl - val;
        carry += ctot;
        __syncthreads();
    }
    if (tid == 0) totals[t] = carry;
}

// ---------------------------------------------------------------------------
// scatter: write packed (src,dst) to sorted position; write rank[e]
// (= sorted position) COALESCED in e-order. bases scanned in-block (40 elems).
// ---------------------------------------------------------------------------
__global__ __launch_bounds__(256) void scatter_kernel(
    const int* __restrict__ src_idx,
    const int* __restrict__ dst_idx,
    const int* __restrict__ counts,   // per-(tile,block) offsets
    const int* __restrict__ totals,
    unsigned* __restrict__ sorted_p,
    int*      __restrict__ rank)
{
    __shared__ int lcnt[NTILE];
    __shared__ int sbase[NTILE];
    __shared__ int lbase[NTILE];
    const int tid = threadIdx.x;
    const int blk = blockIdx.x;
    if (tid < NTILE) lcnt[tid] = 0;
    __syncthreads();

    int ts[4], rs[4], ss[4], ds[4];
    #pragma unroll
    for (int c = 0; c < 4; ++c) {
        const int e = blk * 1024 + c * 256 + tid;
        if (e < N_EDGE) {
            ss[c] = src_idx[e];
            ds[c] = dst_idx[e];
            ts[c] = tile_of(ss[c], ds[c]);
            rs[c] = atomicAdd(&lcnt[ts[c]], 1);
        } else { ts[c] = -1; rs[c] = 0; ss[c] = 0; ds[c] = 0; }
    }
    __syncthreads();
    if (tid == 0) {
        int s = 0;
        for (int i = 0; i < NTILE; ++i) { sbase[i] = s; s += totals[i]; }
    }
    __syncthreads();
    if (tid < NTILE) lbase[tid] = sbase[tid] + counts[tid * NBLK_SORT + blk];
    __syncthreads();

    #pragma unroll
    for (int c = 0; c < 4; ++c) {
        const int e = blk * 1024 + c * 256 + tid;
        if (ts[c] >= 0) {
            const int pos = lbase[ts[c]] + rs[c];
            sorted_p[pos] = pack_sd(ss[c], ds[c]);
            rank[e] = pos;                       // coalesced in e
        }
    }
}

// ---------------------------------------------------------------------------
// Sorted edge kernel: 16 lanes/edge, 4 edges/group, 64 edges/block.
// Reads packed u32 stream; writes res[pos]={loc,std} COALESCED (sorted order).
// XCD-chunk swizzle: each XCD walks a contiguous sorted range
// (tile working set 1.28+2.56=3.84MB fits the 4MB per-XCD L2).
// ---------------------------------------------------------------------------
__global__ __launch_bounds__(256) void edge_sorted_kernel(
    const ushort* __restrict__ cell_zb,
    const ushort* __restrict__ gene_projb,
    const unsigned* __restrict__ sorted_p,
    const float4* __restrict__ cell_p4,
    const float4* __restrict__ gene_p4,
    float2* __restrict__ res)
{
    // bijective XCD chunk swizzle (m204): nwg=15625, q=1953, r=1
    const int wg  = blockIdx.x;
    const int xcd = wg & 7;
    const int sub = wg >> 3;
    const int q = 15625 / 8, r = 15625 % 8;
    const int swz = ((xcd < r) ? xcd * (q + 1) : r * (q + 1) + (xcd - r) * q) + sub;

    const int tid  = threadIdx.x;
    const int lane = tid & 15;
    const int grp  = swz * 16 + (tid >> 4);

    const uint4 p = ((const uint4*)sorted_p)[grp];
    const int s0 = (int)(p.x >> 15), d0 = (int)(p.x & 0x7fffu);
    const int s1 = (int)(p.y >> 15), d1 = (int)(p.y & 0x7fffu);
    const int s2 = (int)(p.z >> 15), d2 = (int)(p.z & 0x7fffu);
    const int s3 = (int)(p.w >> 15), d3 = (int)(p.w & 0x7fffu);

    uint4 a0 = ((const uint4*)(cell_zb    + (long)s0 * DIM))[lane];
    uint4 a1 = ((const uint4*)(cell_zb    + (long)s1 * DIM))[lane];
    uint4 a2 = ((const uint4*)(cell_zb    + (long)s2 * DIM))[lane];
    uint4 a3 = ((const uint4*)(cell_zb    + (long)s3 * DIM))[lane];
    uint4 v0 = ((const uint4*)(gene_projb + (long)d0 * DIM))[lane];
    uint4 v1 = ((const uint4*)(gene_projb + (long)d1 * DIM))[lane];
    uint4 v2 = ((const uint4*)(gene_projb + (long)d2 * DIM))[lane];
    uint4 v3 = ((const uint4*)(gene_projb + (long)d3 * DIM))[lane];

    float dot0 = 0.f, dot1 = 0.f, dot2v = 0.f, dot3 = 0.f;
    dot2(dot0, a0.x, v0.x); dot2(dot0, a0.y, v0.y);
    dot2(dot0, a0.z, v0.z); dot2(dot0, a0.w, v0.w);
    dot2(dot1, a1.x, v1.x); dot2(dot1, a1.y, v1.y);
    dot2(dot1, a1.z, v1.z); dot2(dot1, a1.w, v1.w);
    dot2(dot2v, a2.x, v2.x); dot2(dot2v, a2.y, v2.y);
    dot2(dot2v, a2.z, v2.z); dot2(dot2v, a2.w, v2.w);
    dot2(dot3, a3.x, v3.x); dot2(dot3, a3.y, v3.y);
    dot2(dot3, a3.z, v3.z); dot2(dot3, a3.w, v3.w);

    #define RED(d)                 \
        d += __shfl_xor(d, 1);     \
        d += __shfl_xor(d, 2);     \
        d += __shfl_xor(d, 4);     \
        d += __shfl_xor(d, 8);
    RED(dot0) RED(dot1) RED(dot2v) RED(dot3)
    #undef RED

    if (lane < 4) {
        const float dj = (lane & 2) ? ((lane & 1) ? dot3 : dot2v)
                                    : ((lane & 1) ? dot1 : dot0);
        const int sj   = (lane & 2) ? ((lane & 1) ? s3 : s2)
                                    : ((lane & 1) ? s1 : s0);
        const int djx  = (lane & 2) ? ((lane & 1) ? d3 : d2)
                                    : ((lane & 1) ? d1 : d0);
        const float4 cs = cell_p4[sj];
        const float4 gs = gene_p4[djx];
        res[grp * 4 + lane] =
            make_float2(dj * cs.x * gs.x + cs.y + gs.y, cs.z * gs.z);
    }
}

// ---------------------------------------------------------------------------
// fixup: out[e] = res[rank[e]].  Coalesced rank read + out writes; res reads
// cluster into ~40 short runs per 1024-edge window (scatter block structure)
// -> near-line-efficient. 4 edges per thread.
// ---------------------------------------------------------------------------
__global__ __launch_bounds__(256) void fixup_kernel(
    const int*    __restrict__ rank,
    const float2* __restrict__ res,
    float* __restrict__ out)
{
    const int e0 = (blockIdx.x * 256 + threadIdx.x) * 4;
    if (e0 >= N_EDGE) return;
    const int4 r4 = *(const int4*)(rank + e0);
    const float2 r0 = res[r4.x];
    const float2 r1 = res[r4.y];
    const float2 r2 = res[r4.z];
    const float2 r3 = res[r4.w];
    *(float4*)(out + e0)          = make_float4(r0.x, r1.x, r2.x, r3.x);
    *(float4*)(out + N_EDGE + e0) = make_float4(r0.y, r1.y, r2.y, r3.y);
}

// ---------------------------------------------------------------------------
// Fallback unsorted edge kernel if workspace too small for sort.
// ---------------------------------------------------------------------------
template<bool TAB>
__global__ __launch_bounds__(256) void edge_kernel(
    const ushort* __restrict__ cell_zb,
    const ushort* __restrict__ gene_projb,
    const int*   __restrict__ src_idx,
    const int*   __restrict__ dst_idx,
    const int*   __restrict__ cell_n_id,
    const int*   __restrict__ gene_n_id,
    const float* __restrict__ cell_scale,
    const float* __restrict__ cell_bias,
    const float* __restrict__ cell_std,
    const float* __restrict__ gene_scale,
    const float* __restrict__ gene_bias,
    const float* __restrict__ gene_std,
    const float4* __restrict__ cell_p4,
    const float4* __restrict__ gene_p4,
    float* __restrict__ out)
{
    const int tid  = threadIdx.x;
    const int lane = tid & 15;
    const int grp  = blockIdx.x * 16 + (tid >> 4);
    const int e0   = grp * 4;

    const int4 s4 = ((const int4*)src_idx)[grp];
    const int4 d4 = ((const int4*)dst_idx)[grp];

    uint4 a0 = ((const uint4*)(cell_zb    + (long)s4.x * DIM))[lane];
    uint4 a1 = ((const uint4*)(cell_zb    + (long)s4.y * DIM))[lane];
    uint4 a2 = ((const uint4*)(cell_zb    + (long)s4.z * DIM))[lane];
    uint4 a3 = ((const uint4*)(cell_zb    + (long)s4.w * DIM))[lane];
    uint4 v0 = ((const uint4*)(gene_projb + (long)d4.x * DIM))[lane];
    uint4 v1 = ((const uint4*)(gene_projb + (long)d4.y * DIM))[lane];
    uint4 v2 = ((const uint4*)(gene_projb + (long)d4.z * DIM))[lane];
    uint4 v3 = ((const uint4*)(gene_projb + (long)d4.w * DIM))[lane];

    float dot0 = 0.f, dot1 = 0.f, dot2v = 0.f, dot3 = 0.f;
    dot2(dot0, a0.x, v0.x); dot2(dot0, a0.y, v0.y);
    dot2(dot0, a0.z, v0.z); dot2(dot0, a0.w, v0.w);
    dot2(dot1, a1.x, v1.x); dot2(dot1, a1.y, v1.y);
    dot2(dot1, a1.z, v1.z); dot2(dot1, a1.w, v1.w);
    dot2(dot2v, a2.x, v2.x); dot2(dot2v, a2.y, v2.y);
    dot2(dot2v, a2.z, v2.z); dot2(dot2v, a2.w, v2.w);
    dot2(dot3, a3.x, v3.x); dot2(dot3, a3.y, v3.y);
    dot2(dot3, a3.z, v3.z); dot2(dot3, a3.w, v3.w);

    #define RED(d)                 \
        d += __shfl_xor(d, 1);     \
        d += __shfl_xor(d, 2);     \
        d += __shfl_xor(d, 4);     \
        d += __shfl_xor(d, 8);
    RED(dot0) RED(dot1) RED(dot2v) RED(dot3)
    #undef RED

    if (lane < 4) {
        const float dj = (lane & 2) ? ((lane & 1) ? dot3 : dot2v)
                                    : ((lane & 1) ? dot1 : dot0);
        const int sj   = (lane & 2) ? ((lane & 1) ? s4.w : s4.z)
                                    : ((lane & 1) ? s4.y : s4.x);
        const int djx  = (lane & 2) ? ((lane & 1) ? d4.w : d4.z)
                                    : ((lane & 1) ? d4.y : d4.x);
        float sc_s, b_s, sd_s, sc_d, b_d, sd_d;
        if (TAB) {
            const float4 cs = cell_p4[sj];
            const float4 gs = gene_p4[djx];
            sc_s = cs.x; b_s = cs.y; sd_s = cs.z;
            sc_d = gs.x; b_d = gs.y; sd_d = gs.z;
        } else {
            const int sid = cell_n_id[sj];
            const int did = gene_n_id[djx];
            sc_s = cell_scale[sid]; b_s = cell_bias[sid]; sd_s = cell_std[sid];
            sc_d = gene_scale[did]; b_d = gene_bias[did]; sd_d = gene_std[did];
        }
        const int e = e0 + lane;
        out[e]          = dj * sc_s * sc_d + b_s + b_d;
        out[N_EDGE + e] = sd_s * sd_d;
    }
}

extern "C" void kernel_launch(void* const* d_in, const int* in_sizes, int n_in,
                              void* d_out, int out_size, void* d_ws, size_t ws_size,
                              hipStream_t stream) {
    const float* cell_z     = (const float*)d_in[0];
    const float* gene_z     = (const float*)d_in[1];
    const float* W_gene     = (const float*)d_in[2];
    const float* b_gene     = (const float*)d_in[3];
    const float* cell_scale = (const float*)d_in[4];
    const float* cell_bias  = (const float*)d_in[5];
    const float* cell_std   = (const float*)d_in[6];
    const float* gene_scale = (const float*)d_in[7];
    const float* gene_bias  = (const float*)d_in[8];
    const float* gene_std   = (const float*)d_in[9];
    const int*   src_idx    = (const int*)d_in[10];
    const int*   dst_idx    = (const int*)d_in[11];
    const int*   cell_n_id  = (const int*)d_in[12];
    const int*   gene_n_id  = (const int*)d_in[13];

    // Workspace layout:
    char* ws = (char*)d_ws;
    size_t off = 0;
    ushort* gene_projb = (ushort*)(ws + off); off += (size_t)N_GENE * DIM * 2;  // 5.12 MB
    ushort* cell_zb    = (ushort*)(ws + off); off += (size_t)N_CELL * DIM * 2;  // 25.6 MB
    const size_t base_need = off;

    // tables (1.92 MB)
    float4* cell_p4 = nullptr; float4* gene_p4 = nullptr;
    size_t off_tab = off;
    const size_t tab_need = (size_t)N_CELL * 16 + (size_t)N_GENE * 16;

    // sort structures (~16.2 MB)
    unsigned* sorted_p = nullptr; int* rank = nullptr; float2* res = nullptr;
    int* counts = nullptr; int* totals = nullptr;
    const size_t sort_need = (size_t)N_EDGE * 4      // sorted_p
                           + (size_t)N_EDGE * 4      // rank
                           + (size_t)N_EDGE * 8      // res
                           + (size_t)NTILE * NBLK_SORT * 4 + 256;

    const bool tab = (ws_size >= base_need + tab_need);
    const bool srt = tab && (ws_size >= base_need + tab_need + sort_need);

    if (tab) {
        cell_p4 = (float4*)(ws + off_tab);
        gene_p4 = (float4*)(ws + off_tab + (size_t)N_CELL * 16);
        off = off_tab + tab_need;
    }
    if (srt) {
        sorted_p = (unsigned*)(ws + off); off += (size_t)N_EDGE * 4;
        rank     = (int*)(ws + off);      off += (size_t)N_EDGE * 4;
        res      = (float2*)(ws + off);   off += (size_t)N_EDGE * 8;
        counts   = (int*)(ws + off);      off += (size_t)NTILE * NBLK_SORT * 4;
        totals   = (int*)(ws + off);      off += 256;
    }

    float* out = (float*)d_out;

    prep_kernel<<<NB_PREP, 256, 0, stream>>>(
        gene_z, W_gene, b_gene, gene_projb,
        cell_z, (ushort4*)cell_zb,
        src_idx, dst_idx, cell_n_id, gene_n_id,
        cell_scale, cell_bias, cell_std,
        gene_scale, gene_bias, gene_std,
        cell_p4, gene_p4, counts);

    if (srt) {
        scanA_kernel<<<NTILE, 256, 0, stream>>>(counts, totals);
        scatter_kernel<<<NBLK_SORT, 256, 0, stream>>>(
            src_idx, dst_idx, counts, totals, sorted_p, rank);
        edge_sorted_kernel<<<N_EDGE / 64, 256, 0, stream>>>(
            cell_zb, gene_projb, sorted_p, cell_p4, gene_p4, res);
        fixup_kernel<<<(N_EDGE / 4 + 255) / 256, 256, 0, stream>>>(rank, res, out);
    } else if (tab) {
        edge_kernel<true><<<N_EDGE / 64, 256, 0, stream>>>(
            cell_zb, gene_projb, src_idx, dst_idx, cell_n_id, gene_n_id,
            cell_scale, cell_bias, cell_std, gene_scale, gene_bias, gene_std,
            cell_p4, gene_p4, out);
    } else {
        edge_kernel<false><<<N_EDGE / 64, 256, 0, stream>>>(
            cell_zb, gene_projb, src_idx, dst_idx, cell_n_id, gene_n_id,
            cell_scale, cell_bias, cell_std, gene_scale, gene_bias, gene_std,
            nullptr, nullptr, out);
    }
}